// Round 2
// baseline (411.938 us; speedup 1.0000x reference)
//
#include <hip/hip_runtime.h>
#include <hip/hip_bf16.h>

#define T_SEQ 2048
#define DM    2048
#define NH    16
#define DH    128
#define NBH   32          // B * NH
#define MROWS 4096        // B * T

typedef __bf16 bf16x8 __attribute__((ext_vector_type(8)));
typedef __bf16 bf16x4 __attribute__((ext_vector_type(4)));
typedef float  f32x4  __attribute__((ext_vector_type(4)));

__device__ __forceinline__ void async_copy16(const void* g, void* l) {
  __builtin_amdgcn_global_load_lds((const __attribute__((address_space(1))) void*)g,
                                   (__attribute__((address_space(3))) void*)l, 16, 0, 0);
}

// ---------------- prep kernels ----------------

__global__ void cast_bf16_k(const float* __restrict__ x, __bf16* __restrict__ xb) {
  int i = (blockIdx.x * 256 + threadIdx.x) * 4;
  float4 v = *reinterpret_cast<const float4*>(x + i);
  bf16x4 o;
  o[0] = (__bf16)v.x; o[1] = (__bf16)v.y; o[2] = (__bf16)v.z; o[3] = (__bf16)v.w;
  *reinterpret_cast<bf16x4*>(xb + i) = o;
}

// W [K][N] f32 -> WT [N][K] bf16
__global__ void transpose_cast_w(const float* __restrict__ W, __bf16* __restrict__ WT,
                                 int K, int N) {
  __shared__ float tile[32][33];
  int n0 = blockIdx.x * 32, k0 = blockIdx.y * 32;
  int tx = threadIdx.x, ty = threadIdx.y;
  #pragma unroll
  for (int i = 0; i < 4; i++)
    tile[ty + i * 8][tx] = W[(size_t)(k0 + ty + i * 8) * N + n0 + tx];
  __syncthreads();
  #pragma unroll
  for (int i = 0; i < 4; i++)
    WT[(size_t)(n0 + ty + i * 8) * K + k0 + tx] = (__bf16)tile[tx][ty + i * 8];
}

// Vb [BH][T][D] bf16 -> Vtb [BH][D][T] bf16
__global__ void transpose_v(const __bf16* __restrict__ Vb, __bf16* __restrict__ Vtb) {
  __shared__ __bf16 tile[32][34];
  int t0 = blockIdx.x * 32, d0 = blockIdx.y * 32, bh = blockIdx.z;
  const __bf16* src = Vb + (size_t)bh * T_SEQ * DH;
  __bf16* dst = Vtb + (size_t)bh * DH * T_SEQ;
  int tx = threadIdx.x, ty = threadIdx.y;
  #pragma unroll
  for (int i = 0; i < 4; i++)
    tile[ty + i * 8][tx] = src[(size_t)(t0 + ty + i * 8) * DH + d0 + tx];
  __syncthreads();
  #pragma unroll
  for (int i = 0; i < 4; i++)
    dst[(size_t)(d0 + ty + i * 8) * T_SEQ + t0 + tx] = tile[tx][ty + i * 8];
}

// ---------------- 8-phase GEMM (C = A * Bt^T), BM=128 BN=256 BK=64 ----------------
// LDS layout per tile: [rows][64 bf16] = 128 B/row, XOR-chunk-swizzled:
// LDS(row, c) holds global (row, c ^ (row&7)); read applies the same XOR.
// Staged via global_load_lds (linear dest) with inverse-swizzled global source.

__device__ __forceinline__ bf16x8 rds(const __bf16* base, int row, int chunk) {
  return *reinterpret_cast<const bf16x8*>(
      reinterpret_cast<const char*>(base) + row * 128 + (((chunk) ^ (row & 7)) << 4));
}

// stage A half-tile h (64 rows, 8 KB): 1 global_load_lds per wave
__device__ __forceinline__ void stA(const __bf16* g, int K, int kt, int h,
                                    char* lds, int wave, int lane) {
  int off = wave * 1024;
  int r = h * 64 + wave * 8 + (lane >> 3);
  int c = lane & 7;
  const char* src = (const char*)g + (size_t)r * (K * 2) + kt * 128 + ((c ^ (r & 7)) << 4);
  async_copy16(src, lds + h * 8192 + off);
}

// stage B half-tile h (128 rows, 16 KB): 2 global_load_lds per wave
__device__ __forceinline__ void stB(const __bf16* g, int K, int kt, int h,
                                    char* lds, int wave, int lane) {
  #pragma unroll
  for (int j = 0; j < 2; j++) {
    int off = j * 8192 + wave * 1024;
    int r = h * 128 + j * 64 + wave * 8 + (lane >> 3);
    int c = lane & 7;
    const char* src = (const char*)g + (size_t)r * (K * 2) + kt * 128 + ((c ^ (r & 7)) << 4);
    async_copy16(src, lds + h * 16384 + off);
  }
}

#define BARRIER() asm volatile("s_barrier" ::: "memory")

template <int EPI>
__global__ __launch_bounds__(512, 2) void gemm8p(
    const __bf16* __restrict__ A, const __bf16* __restrict__ Bt, int K, int gx,
    const float* __restrict__ bias,
    const float* __restrict__ fcos, const float* __restrict__ fsin,
    __bf16* __restrict__ Qb, __bf16* __restrict__ Kb, __bf16* __restrict__ Vb,
    float* __restrict__ kout, float* __restrict__ vout,
    float* __restrict__ outp) {
  __shared__ __bf16 As[2][128 * 64];   // 2 x 16 KB
  __shared__ __bf16 Bs[2][256 * 64];   // 2 x 32 KB   (total 96 KB)
  const int tid = threadIdx.x, lane = tid & 63, wave = tid >> 6;
  const int hi = lane >> 4, lo = lane & 15;
  const int wm = (wave & 1) * 64, wn = (wave >> 1) * 64;
  // bijective XCD swizzle (gridDim.x divisible by 8)
  const int nwg = (int)gridDim.x;
  const int wg = (int)blockIdx.x;
  const int swz = (wg & 7) * (nwg >> 3) + (wg >> 3);
  const int by = swz / gx, bx = swz % gx;
  const __bf16* Ab = A + (size_t)by * 128 * K;
  const __bf16* Bb = Bt + (size_t)bx * 256 * K;
  f32x4 acc[4][4] = {};
  const int NK = K >> 6;

  // prologue: tile0 (B0,A0,A1,B1) + tile1 (B0,A0) = 9 loads/wave
  stB(Bb, K, 0, 0, (char*)Bs[0], wave, lane);
  stA(Ab, K, 0, 0, (char*)As[0], wave, lane);
  stA(Ab, K, 0, 1, (char*)As[0], wave, lane);
  stB(Bb, K, 0, 1, (char*)Bs[0], wave, lane);
  stB(Bb, K, 1, 0, (char*)Bs[1], wave, lane);
  stA(Ab, K, 1, 0, (char*)As[1], wave, lane);
  asm volatile("s_waitcnt vmcnt(3)" ::: "memory");
  BARRIER();

  bf16x8 aR[2][2], bR[4][2];
  for (int t = 0; t < NK; ++t) {
    const __bf16* Ac = As[t & 1];
    const __bf16* Bc = Bs[t & 1];
    char* An = (char*)As[(t + 1) & 1];
    char* Bn = (char*)Bs[(t + 1) & 1];
    char* An2 = (char*)As[t & 1];      // t+2 shares parity with t
    char* Bn2 = (char*)Bs[t & 1];
    const bool s1 = (t + 1 < NK), s2 = (t + 2 < NK);

    // ---- phase 0: quad (mq0, nq0) ----
    #pragma unroll
    for (int i = 0; i < 2; i++) {
      aR[i][0] = rds(Ac, wm + i * 16 + lo, hi);
      aR[i][1] = rds(Ac, wm + i * 16 + lo, 4 + hi);
      bR[i][0] = rds(Bc, wn + i * 16 + lo, hi);
      bR[i][1] = rds(Bc, wn + i * 16 + lo, 4 + hi);
    }
    if (s1) stA(Ab, K, t + 1, 1, An, wave, lane);
    BARRIER();
    __builtin_amdgcn_s_setprio(1);
    #pragma unroll
    for (int i = 0; i < 2; i++)
      #pragma unroll
      for (int j = 0; j < 2; j++) {
        acc[i][j] = __builtin_amdgcn_mfma_f32_16x16x32_bf16(aR[i][0], bR[j][0], acc[i][j], 0, 0, 0);
        acc[i][j] = __builtin_amdgcn_mfma_f32_16x16x32_bf16(aR[i][1], bR[j][1], acc[i][j], 0, 0, 0);
      }
    __builtin_amdgcn_s_setprio(0);
    BARRIER();

    // ---- phase 1: quad (mq0, nq1) ----
    #pragma unroll
    for (int j = 2; j < 4; j++) {
      bR[j][0] = rds(Bc, wn + j * 16 + lo, hi);
      bR[j][1] = rds(Bc, wn + j * 16 + lo, 4 + hi);
    }
    if (s1) stB(Bb, K, t + 1, 1, Bn, wave, lane);
    BARRIER();
    __builtin_amdgcn_s_setprio(1);
    #pragma unroll
    for (int i = 0; i < 2; i++)
      #pragma unroll
      for (int j = 2; j < 4; j++) {
        acc[i][j] = __builtin_amdgcn_mfma_f32_16x16x32_bf16(aR[i][0], bR[j][0], acc[i][j], 0, 0, 0);
        acc[i][j] = __builtin_amdgcn_mfma_f32_16x16x32_bf16(aR[i][1], bR[j][1], acc[i][j], 0, 0, 0);
      }
    __builtin_amdgcn_s_setprio(0);
    BARRIER();

    // ---- phase 2: quad (mq1, nq0) ----
    #pragma unroll
    for (int i = 0; i < 2; i++) {
      aR[i][0] = rds(Ac, wm + 32 + i * 16 + lo, hi);
      aR[i][1] = rds(Ac, wm + 32 + i * 16 + lo, 4 + hi);
    }
    if (s2) stB(Bb, K, t + 2, 0, Bn2, wave, lane);
    BARRIER();
    __builtin_amdgcn_s_setprio(1);
    #pragma unroll
    for (int i = 0; i < 2; i++)
      #pragma unroll
      for (int j = 0; j < 2; j++) {
        acc[2 + i][j] = __builtin_amdgcn_mfma_f32_16x16x32_bf16(aR[i][0], bR[j][0], acc[2 + i][j], 0, 0, 0);
        acc[2 + i][j] = __builtin_amdgcn_mfma_f32_16x16x32_bf16(aR[i][1], bR[j][1], acc[2 + i][j], 0, 0, 0);
      }
    __builtin_amdgcn_s_setprio(0);
    BARRIER();

    // ---- phase 3: quad (mq1, nq1) ----
    if (s2) stA(Ab, K, t + 2, 0, An2, wave, lane);
    BARRIER();
    __builtin_amdgcn_s_setprio(1);
    #pragma unroll
    for (int i = 0; i < 2; i++)
      #pragma unroll
      for (int j = 2; j < 4; j++) {
        acc[2 + i][j] = __builtin_amdgcn_mfma_f32_16x16x32_bf16(aR[i][0], bR[j][0], acc[2 + i][j], 0, 0, 0);
        acc[2 + i][j] = __builtin_amdgcn_mfma_f32_16x16x32_bf16(aR[i][1], bR[j][1], acc[2 + i][j], 0, 0, 0);
      }
    __builtin_amdgcn_s_setprio(0);
    // tile boundary: counted wait — tail (B0,A0 of t+2) = 3 loads stays in flight
    if (s2) asm volatile("s_waitcnt vmcnt(3)" ::: "memory");
    else    asm volatile("s_waitcnt vmcnt(0)" ::: "memory");
    BARRIER();
  }

  // epilogue. C layout per 16x16 frag: row = hi*4 + r, col = lo (verified m89/m91)
  #pragma unroll
  for (int j = 0; j < 4; j++) {
    int n = bx * 256 + wn + j * 16 + lo;
    float bv = bias[n];
    if (EPI == 1) {
      int which = n >> 11, wn2 = n & 2047, h = wn2 >> 7, d = wn2 & 127, jj = d >> 1;
      #pragma unroll
      for (int i = 0; i < 4; i++) {
        #pragma unroll
        for (int r = 0; r < 4; r++) {
          int row = by * 128 + wm + i * 16 + hi * 4 + r;
          int b = row >> 11, tt = row & 2047;
          float v = acc[i][j][r] + bv;
          float other = __shfl_xor(v, 1, 64);   // rope pair partner (cols n, n^1)
          float res = v;
          if (which < 2) {
            float c = fcos[tt * 64 + jj], s = fsin[tt * 64 + jj];
            res = (d & 1) ? (other * s + v * c) : (v * c - other * s);
          }
          size_t idx = (((size_t)(b * NH + h)) * T_SEQ + tt) * DH + d;
          if (which == 0) {
            Qb[idx] = (__bf16)res;
          } else if (which == 1) {
            Kb[idx] = (__bf16)res; kout[idx] = res;
          } else {
            Vb[idx] = (__bf16)res; vout[idx] = res;
          }
        }
      }
    } else {
      #pragma unroll
      for (int i = 0; i < 4; i++) {
        #pragma unroll
        for (int r = 0; r < 4; r++) {
          int row = by * 128 + wm + i * 16 + hi * 4 + r;
          outp[(size_t)row * DM + n] = acc[i][j][r] + bv;
        }
      }
    }
  }
}

// ---------------- flash attention ----------------
// LDS tiles are [128 rows][256B rows], chunk-swizzled: chunk' = chunk ^ (row&7).
// Staged via global_load_lds (linear dest) with inverse-swizzled global source.

__device__ __forceinline__ void stage_swz(const __bf16* g, int rstride,
                                          __bf16* lds, int tid) {
  const int wave = tid >> 6, lane = tid & 63;
  const char* gb = (const char*)g;
  char* lb = (char*)lds;
  #pragma unroll
  for (int j = 0; j < 8; j++) {
    int off = j * 4096 + wave * 1024;               // wave-uniform LDS base
    int r = (off >> 8) + (lane >> 4);
    int c = lane & 15;
    const char* gs = gb + (size_t)r * (rstride * 2) + ((c ^ (r & 7)) << 4);
    async_copy16(gs, lb + off);
  }
}

__device__ __forceinline__ bf16x8 lds_frag(const __bf16* base, int row, int chunk) {
  return *reinterpret_cast<const bf16x8*>(
      reinterpret_cast<const char*>(base) + row * 256 + ((chunk ^ (row & 7)) << 4));
}

__global__ __launch_bounds__(256, 1) void attn_fwd(
    const __bf16* __restrict__ Qb, const __bf16* __restrict__ Kb,
    const __bf16* __restrict__ Vtb, __bf16* __restrict__ att_out) {
  __shared__ __bf16 Qs[128 * 128];
  __shared__ __bf16 Ks[128 * 128];
  __shared__ __bf16 Vts[128 * 128];
  __shared__ __bf16 Ps[4 * 32 * 128];   // per-wave P tile [32 q][128 s]
  const int tid = threadIdx.x, lane = tid & 63, wave = tid >> 6;
  const int hi = lane >> 4, lo = lane & 15;
  const int bh = blockIdx.y, b = bh >> 4, h = bh & 15;
  const __bf16* Qg = Qb + (size_t)bh * T_SEQ * DH;
  const __bf16* Kg = Kb + (size_t)bh * T_SEQ * DH;
  const __bf16* Vg = Vtb + (size_t)bh * DH * T_SEQ;
  const float scale = 0.08838834764831845f;   // 1/sqrt(128)
  const float L2E = 1.4426950408889634f;

  for (int pass = 0; pass < 2; ++pass) {
    int qi = pass ? (15 - blockIdx.x) : blockIdx.x;
    int q0 = qi * 128;
    __syncthreads();                           // all waves done with prev pass LDS
    stage_swz(Qg + (size_t)q0 * DH, DH, Qs, tid);
    f32x4 oacc[8][2] = {};
    float m0 = -3e38f, m1 = -3e38f, l0 = 0.f, l1 = 0.f;
    const int qgl0 = q0 + wave * 32 + lo;
    const int qgl1 = qgl0 + 16;

    for (int kt = 0; kt <= qi; ++kt) {
      __syncthreads();                         // prev tile reads done
      stage_swz(Kg + (size_t)kt * 128 * DH, DH, Ks, tid);
      stage_swz(Vg + (size_t)kt * 128, T_SEQ, Vts, tid);
      __syncthreads();                         // drains vmcnt(0): K/V (and Q) ready

      // S^T = K · Q^T : A = K[s][d], B = Q^T[d][q]; C: row=s (hi*4+r), col=q (lo)
      f32x4 sacc[8][2] = {};
      #pragma unroll
      for (int ks = 0; ks < 4; ++ks) {
        bf16x8 bq0 = lds_frag(Qs, wave * 32 + lo, ks * 4 + hi);
        bf16x8 bq1 = lds_frag(Qs, wave * 32 + 16 + lo, ks * 4 + hi);
        #pragma unroll
        for (int sf = 0; sf < 8; ++sf) {
          bf16x8 ak = lds_frag(Ks, sf * 16 + lo, ks * 4 + hi);
          sacc[sf][0] = __builtin_amdgcn_mfma_f32_16x16x32_bf16(ak, bq0, sacc[sf][0], 0, 0, 0);
          sacc[sf][1] = __builtin_amdgcn_mfma_f32_16x16x32_bf16(ak, bq1, sacc[sf][1], 0, 0, 0);
        }
      }
      const bool diag = (kt == qi);
      #pragma unroll
      for (int qf = 0; qf < 2; ++qf) {
        const int qgl = qf ? qgl1 : qgl0;
        float mold = qf ? m1 : m0;
        float mx = -3e38f;
        #pragma unroll
        for (int sf = 0; sf < 8; ++sf)
          #pragma unroll
          for (int r = 0; r < 4; ++r) {
            float v = sacc[sf][qf][r] * scale;
            if (diag && (kt * 128 + sf * 16 + hi * 4 + r) > qgl) v = -3e38f;
            sacc[sf][qf][r] = v;
            mx = fmaxf(mx, v);
          }
        mx = fmaxf(mx, __shfl_xor(mx, 16, 64));
        mx = fmaxf(mx, __shfl_xor(mx, 32, 64));
        float mnew = fmaxf(mold, mx);
        float alpha = __builtin_exp2f((mold - mnew) * L2E);
        if (qf) m1 = mnew; else m0 = mnew;
        float rs = 0.f;
        #pragma unroll
        for (int sf = 0; sf < 8; ++sf)
          #pragma unroll
          for (int r = 0; r < 4; ++r) {
            float p = __builtin_exp2f((sacc[sf][qf][r] - mnew) * L2E);
            sacc[sf][qf][r] = p;
            rs += p;
          }
        rs += __shfl_xor(rs, 16, 64);
        rs += __shfl_xor(rs, 32, 64);
        if (qf) l1 = l1 * alpha + rs; else l0 = l0 * alpha + rs;
        #pragma unroll
        for (int df = 0; df < 8; ++df) {
          oacc[df][qf][0] *= alpha; oacc[df][qf][1] *= alpha;
          oacc[df][qf][2] *= alpha; oacc[df][qf][3] *= alpha;
        }
        // write P tile: lane's 4 vals are contiguous s at row q_loc -> one b64
        const int q_loc = qf * 16 + lo;
        #pragma unroll
        for (int sf = 0; sf < 8; ++sf) {
          bf16x4 pk;
          pk[0] = (__bf16)sacc[sf][qf][0]; pk[1] = (__bf16)sacc[sf][qf][1];
          pk[2] = (__bf16)sacc[sf][qf][2]; pk[3] = (__bf16)sacc[sf][qf][3];
          int cb = sf * 32 + hi * 8;
          int chunk = cb >> 4, rem = cb & 15;
          char* p = (char*)Ps + wave * 8192 + q_loc * 256 +
                    (((chunk ^ (q_loc & 7)) << 4) | rem);
          *reinterpret_cast<bf16x4*>(p) = pk;
        }
      }
      // PV: O^T += V^T · P^T : A = V^T[d][s] (Vts rows), B = P[q][s] rows
      const __bf16* Pw = Ps + wave * 4096;
      #pragma unroll
      for (int ks = 0; ks < 4; ++ks) {
        bf16x8 bp0 = lds_frag(Pw, lo, ks * 4 + hi);
        bf16x8 bp1 = lds_frag(Pw, 16 + lo, ks * 4 + hi);
        #pragma unroll
        for (int df = 0; df < 8; ++df) {
          bf16x8 av = lds_frag(Vts, df * 16 + lo, ks * 4 + hi);
          oacc[df][0] = __builtin_amdgcn_mfma_f32_16x16x32_bf16(av, bp0, oacc[df][0], 0, 0, 0);
          oacc[df][1] = __builtin_amdgcn_mfma_f32_16x16x32_bf16(av, bp1, oacc[df][1], 0, 0, 0);
        }
      }
    } // kt

    // epilogue: O^T lane holds d = df*16 + hi*4 + r, q = qf*16 + lo
    #pragma unroll
    for (int qf = 0; qf < 2; ++qf) {
      float inv = 1.0f / (qf ? l1 : l0);
      int qrow = b * T_SEQ + q0 + wave * 32 + qf * 16 + lo;
      #pragma unroll
      for (int df = 0; df < 8; ++df) {
        bf16x4 pk;
        pk[0] = (__bf16)(oacc[df][qf][0] * inv);
        pk[1] = (__bf16)(oacc[df][qf][1] * inv);
        pk[2] = (__bf16)(oacc[df][qf][2] * inv);
        pk[3] = (__bf16)(oacc[df][qf][3] * inv);
        int d = df * 16 + hi * 4;
        *reinterpret_cast<bf16x4*>(att_out + (size_t)qrow * DM + h * DH + d) = pk;
      }
    }
  } // pass
}

// ---------------- launch ----------------

extern "C" void kernel_launch(void* const* d_in, const int* in_sizes, int n_in,
                              void* d_out, int out_size, void* d_ws, size_t ws_size,
                              hipStream_t stream) {
  const float* x     = (const float*)d_in[0];
  // d_in[1] = causal mask: ignored (mask applied analytically)
  const float* fcos  = (const float*)d_in[2];
  const float* fsin  = (const float*)d_in[3];
  const float* Wqkv  = (const float*)d_in[4];
  const float* bqkv  = (const float*)d_in[5];
  const float* Wproj = (const float*)d_in[6];
  const float* bproj = (const float*)d_in[7];
  float* out  = (float*)d_out;
  float* kout = out + (size_t)8388608;
  float* vout = out + (size_t)16777216;

  char* ws = (char*)d_ws;
  __bf16* xb     = (__bf16*)(ws);                 // 16 MiB; reused as att_out later
  __bf16* WqkvT  = (__bf16*)(ws + 16777216);      // 24 MiB
  __bf16* WprojT = (__bf16*)(ws + 41943040);      // 8 MiB
  __bf16* Qb     = (__bf16*)(ws + 50331648);      // 16 MiB
  __bf16* Kb     = (__bf16*)(ws + 67108864);      // 16 MiB
  __bf16* Vb     = (__bf16*)(ws + 83886080);      // 16 MiB
  __bf16* Vtb    = (__bf16*)(ws + 100663296);     // 16 MiB  (total 112 MiB)
  __bf16* att    = xb;                            // alias: xb dead after gemm1

  cast_bf16_k<<<8192, 256, 0, stream>>>(x, xb);
  transpose_cast_w<<<dim3(192, 64), dim3(32, 8), 0, stream>>>(Wqkv, WqkvT, DM, 3 * DM);
  transpose_cast_w<<<dim3(64, 64), dim3(32, 8), 0, stream>>>(Wproj, WprojT, DM, DM);
  // QKV: M=4096 (by 0..31), N=6144 (bx 0..23) -> 768 blocks (3/CU, even)
  gemm8p<1><<<768, 512, 0, stream>>>(xb, WqkvT, DM, 24, bqkv, fcos, fsin,
                                     Qb, Kb, Vb, kout, vout, nullptr);
  transpose_v<<<dim3(64, 4, NBH), dim3(32, 8), 0, stream>>>(Vb, Vtb);
  attn_fwd<<<dim3(8, NBH), 256, 0, stream>>>(Qb, Kb, Vtb, att);
  // proj: M=4096, N=2048 (bx 0..7) -> 256 blocks (1/CU, even)
  gemm8p<0><<<256, 512, 0, stream>>>(att, WprojT, DM, 8, bproj, nullptr, nullptr,
                                     nullptr, nullptr, nullptr, nullptr, nullptr, out);
}

// Round 3
// 406.663 us; speedup vs baseline: 1.0130x; 1.0130x over previous
//
#include <hip/hip_runtime.h>
#include <hip/hip_bf16.h>

#define T_SEQ 2048
#define DM    2048
#define NH    16
#define DH    128
#define NBH   32          // B * NH
#define MROWS 4096        // B * T

typedef __bf16 bf16x8 __attribute__((ext_vector_type(8)));
typedef __bf16 bf16x4 __attribute__((ext_vector_type(4)));
typedef float  f32x4  __attribute__((ext_vector_type(4)));

#define MFMA16 __builtin_amdgcn_mfma_f32_16x16x32_bf16
#define BARRIER() asm volatile("s_barrier" ::: "memory")

__device__ __forceinline__ void async_copy16(const void* g, void* l) {
  __builtin_amdgcn_global_load_lds((const __attribute__((address_space(1))) void*)g,
                                   (__attribute__((address_space(3))) void*)l, 16, 0, 0);
}

// ---------------- prep kernels ----------------

__global__ void cast_bf16_k(const float* __restrict__ x, __bf16* __restrict__ xb) {
  int i = (blockIdx.x * 256 + threadIdx.x) * 4;
  float4 v = *reinterpret_cast<const float4*>(x + i);
  bf16x4 o;
  o[0] = (__bf16)v.x; o[1] = (__bf16)v.y; o[2] = (__bf16)v.z; o[3] = (__bf16)v.w;
  *reinterpret_cast<bf16x4*>(xb + i) = o;
}

// W [K][N] f32 -> WT [N][K] bf16
__global__ void transpose_cast_w(const float* __restrict__ W, __bf16* __restrict__ WT,
                                 int K, int N) {
  __shared__ float tile[32][33];
  int n0 = blockIdx.x * 32, k0 = blockIdx.y * 32;
  int tx = threadIdx.x, ty = threadIdx.y;
  #pragma unroll
  for (int i = 0; i < 4; i++)
    tile[ty + i * 8][tx] = W[(size_t)(k0 + ty + i * 8) * N + n0 + tx];
  __syncthreads();
  #pragma unroll
  for (int i = 0; i < 4; i++)
    WT[(size_t)(n0 + ty + i * 8) * K + k0 + tx] = (__bf16)tile[tx][ty + i * 8];
}

// Vb [BH][T][D] bf16 -> Vtb [BH][D][T] bf16
__global__ void transpose_v(const __bf16* __restrict__ Vb, __bf16* __restrict__ Vtb) {
  __shared__ __bf16 tile[32][34];
  int t0 = blockIdx.x * 32, d0 = blockIdx.y * 32, bh = blockIdx.z;
  const __bf16* src = Vb + (size_t)bh * T_SEQ * DH;
  __bf16* dst = Vtb + (size_t)bh * DH * T_SEQ;
  int tx = threadIdx.x, ty = threadIdx.y;
  #pragma unroll
  for (int i = 0; i < 4; i++)
    tile[ty + i * 8][tx] = src[(size_t)(t0 + ty + i * 8) * DH + d0 + tx];
  __syncthreads();
  #pragma unroll
  for (int i = 0; i < 4; i++)
    dst[(size_t)(d0 + ty + i * 8) * T_SEQ + t0 + tx] = tile[tx][ty + i * 8];
}

// -------- 8-phase GEMM (C = A * Bt^T), BM=BN=256, BK=64, m201 geometry --------
// 8 waves (2M x 4N), per-wave 128x64 output, 16 MFMA per phase.
// LDS rows are 64 bf16 = 128 B, chunk-XOR swizzled: LDS(row, c) holds global
// (row, c ^ (row&7)); staged via global_load_lds (linear dest) with
// inverse-swizzled global source; reads apply the same XOR.

__device__ __forceinline__ bf16x8 rds(const __bf16* base, int row, int chunk) {
  return *reinterpret_cast<const bf16x8*>(
      reinterpret_cast<const char*>(base) + row * 128 + ((chunk ^ (row & 7)) << 4));
}

// stage one half-tile h (128 rows x 64 cols, 16 KB): 2 global_load_lds per wave
__device__ __forceinline__ void stHalf(const __bf16* g, int K, int kt, int h,
                                       char* lds, int wave, int lane) {
  #pragma unroll
  for (int j = 0; j < 2; j++) {
    int r = h * 128 + wave * 16 + j * 8 + (lane >> 3);
    int c = lane & 7;
    const char* src = (const char*)g + (size_t)r * (K * 2) + kt * 128 + ((c ^ (r & 7)) << 4);
    async_copy16(src, lds + h * 16384 + wave * 2048 + j * 1024);
  }
}

template <int EPI>
__global__ __launch_bounds__(512, 2) void gemm8p(
    const __bf16* __restrict__ A, const __bf16* __restrict__ Bt, int K, int gx,
    const float* __restrict__ bias,
    const float* __restrict__ fcos, const float* __restrict__ fsin,
    __bf16* __restrict__ Qb, __bf16* __restrict__ Kb, __bf16* __restrict__ Vb,
    float* __restrict__ kout, float* __restrict__ vout,
    float* __restrict__ outp) {
  __shared__ __bf16 As[2][256 * 64];   // 2 x 32 KB
  __shared__ __bf16 Bs[2][256 * 64];   // 2 x 32 KB  (128 KB total)
  const int tid = threadIdx.x, lane = tid & 63, wave = tid >> 6;
  const int hi = lane >> 4, lo = lane & 15;
  const int wm = (wave >> 2) * 128, wn = (wave & 3) * 64;
  const int wg = (int)blockIdx.x;
  const int by = wg / gx, bx = wg % gx;   // natural raster: bx fastest (XCD rr)
  const __bf16* Ab = A + (size_t)by * 256 * K;
  const __bf16* Bb = Bt + (size_t)bx * 256 * K;
  f32x4 acc[8][4] = {};
  const int NK = K >> 6, NI = NK >> 1;   // K=2048 -> NK=32, NI=16

  // prologue: tile0 (4 halves -> buf0), tile1 B-halves -> buf1
  stHalf(Bb, K, 0, 0, (char*)Bs[0], wave, lane);
  stHalf(Bb, K, 0, 1, (char*)Bs[0], wave, lane);
  stHalf(Ab, K, 0, 0, (char*)As[0], wave, lane);
  stHalf(Ab, K, 0, 1, (char*)As[0], wave, lane);
  stHalf(Bb, K, 1, 0, (char*)Bs[1], wave, lane);
  stHalf(Bb, K, 1, 1, (char*)Bs[1], wave, lane);
  asm volatile("s_waitcnt vmcnt(4)" ::: "memory");
  BARRIER();

  bf16x8 aR[4][2], bR[4][2];
  for (int it = 0; it < NI; ++it) {
    #pragma unroll
    for (int g = 0; g < 2; ++g) {
      const int t = 2 * it + g;           // even tiles in buf0, odd in buf1
      const __bf16* Ac = As[g];
      const __bf16* Bc = Bs[g];
      char* Adst = (char*)As[g ^ 1];      // A(t+1)
      char* Bdst = (char*)Bs[g];          // B(t+2)
      const bool sA = (t + 1 < NK);
      const bool sB = (t + 2 < NK);

      // ---- phase 0: quadrant (m-half 0, n-half 0) ----
      #pragma unroll
      for (int m = 0; m < 4; ++m) {
        aR[m][0] = rds(Ac, wm + m * 16 + lo, hi);
        aR[m][1] = rds(Ac, wm + m * 16 + lo, 4 + hi);
      }
      #pragma unroll
      for (int n = 0; n < 2; ++n) {
        bR[n][0] = rds(Bc, wn + n * 16 + lo, hi);
        bR[n][1] = rds(Bc, wn + n * 16 + lo, 4 + hi);
      }
      if (sA) stHalf(Ab, K, t + 1, 0, Adst, wave, lane);
      BARRIER();
      __builtin_amdgcn_s_setprio(1);
      #pragma unroll
      for (int m = 0; m < 4; ++m)
        #pragma unroll
        for (int n = 0; n < 2; ++n) {
          acc[m][n] = MFMA16(aR[m][0], bR[n][0], acc[m][n], 0, 0, 0);
          acc[m][n] = MFMA16(aR[m][1], bR[n][1], acc[m][n], 0, 0, 0);
        }
      __builtin_amdgcn_s_setprio(0);
      BARRIER();

      // ---- phase 1: quadrant (m0, n1) ----
      #pragma unroll
      for (int n = 2; n < 4; ++n) {
        bR[n][0] = rds(Bc, wn + n * 16 + lo, hi);
        bR[n][1] = rds(Bc, wn + n * 16 + lo, 4 + hi);
      }
      if (sA) stHalf(Ab, K, t + 1, 1, Adst, wave, lane);
      BARRIER();
      __builtin_amdgcn_s_setprio(1);
      #pragma unroll
      for (int m = 0; m < 4; ++m)
        #pragma unroll
        for (int n = 2; n < 4; ++n) {
          acc[m][n] = MFMA16(aR[m][0], bR[n][0], acc[m][n], 0, 0, 0);
          acc[m][n] = MFMA16(aR[m][1], bR[n][1], acc[m][n], 0, 0, 0);
        }
      __builtin_amdgcn_s_setprio(0);
      BARRIER();

      // ---- phase 2: quadrant (m1, n0) ----  (B(t) LDS reads done after ph1)
      #pragma unroll
      for (int m = 0; m < 4; ++m) {
        aR[m][0] = rds(Ac, wm + 64 + m * 16 + lo, hi);
        aR[m][1] = rds(Ac, wm + 64 + m * 16 + lo, 4 + hi);
      }
      if (sB) stHalf(Bb, K, t + 2, 0, Bdst, wave, lane);
      BARRIER();
      __builtin_amdgcn_s_setprio(1);
      #pragma unroll
      for (int m = 0; m < 4; ++m)
        #pragma unroll
        for (int n = 0; n < 2; ++n) {
          acc[4 + m][n] = MFMA16(aR[m][0], bR[n][0], acc[4 + m][n], 0, 0, 0);
          acc[4 + m][n] = MFMA16(aR[m][1], bR[n][1], acc[4 + m][n], 0, 0, 0);
        }
      __builtin_amdgcn_s_setprio(0);
      BARRIER();

      // ---- phase 3: quadrant (m1, n1) ----  (A(t) LDS reads done after ph2)
      if (sB) stHalf(Bb, K, t + 2, 1, Bdst, wave, lane);
      BARRIER();
      __builtin_amdgcn_s_setprio(1);
      #pragma unroll
      for (int m = 0; m < 4; ++m)
        #pragma unroll
        for (int n = 2; n < 4; ++n) {
          acc[4 + m][n] = MFMA16(aR[m][0], bR[n][0], acc[4 + m][n], 0, 0, 0);
          acc[4 + m][n] = MFMA16(aR[m][1], bR[n][1], acc[4 + m][n], 0, 0, 0);
        }
      __builtin_amdgcn_s_setprio(0);
      // K-tile boundary: counted wait — keep 2 half-tiles (4 loads) in flight
      if (sB) asm volatile("s_waitcnt vmcnt(4)" ::: "memory");
      else    asm volatile("s_waitcnt vmcnt(0)" ::: "memory");
      BARRIER();
    } // g
  } // it

  // epilogue. C frag layout: row = hi*4 + r, col = lo (verified m89/m91)
  #pragma unroll
  for (int j = 0; j < 4; j++) {
    int n = bx * 256 + wn + j * 16 + lo;
    float bv = bias[n];
    if (EPI == 1) {
      int which = n >> 11, wn2 = n & 2047, h = wn2 >> 7, d = wn2 & 127, jj = d >> 1;
      #pragma unroll
      for (int i = 0; i < 8; i++) {
        #pragma unroll
        for (int r = 0; r < 4; r++) {
          int row = by * 256 + wm + i * 16 + hi * 4 + r;
          int b = row >> 11, tt = row & 2047;
          float v = acc[i][j][r] + bv;
          float other = __shfl_xor(v, 1, 64);   // rope pair partner (cols n, n^1)
          float res = v;
          if (which < 2) {
            float c = fcos[tt * 64 + jj], s = fsin[tt * 64 + jj];
            res = (d & 1) ? (other * s + v * c) : (v * c - other * s);
          }
          size_t idx = (((size_t)(b * NH + h)) * T_SEQ + tt) * DH + d;
          if (which == 0) {
            Qb[idx] = (__bf16)res;
          } else if (which == 1) {
            Kb[idx] = (__bf16)res; kout[idx] = res;
          } else {
            Vb[idx] = (__bf16)res; vout[idx] = res;
          }
        }
      }
    } else {
      #pragma unroll
      for (int i = 0; i < 8; i++) {
        #pragma unroll
        for (int r = 0; r < 4; r++) {
          int row = by * 256 + wm + i * 16 + hi * 4 + r;
          outp[(size_t)row * DM + n] = acc[i][j][r] + bv;
        }
      }
    }
  }
}

// ---------------- flash attention ----------------
// LDS tiles are [128 rows][256B rows], chunk-swizzled: chunk' = chunk ^ (row&7).
// Staged via global_load_lds (linear dest) with inverse-swizzled global source.

__device__ __forceinline__ void stage_swz(const __bf16* g, int rstride,
                                          __bf16* lds, int tid) {
  const int wave = tid >> 6, lane = tid & 63;
  const char* gb = (const char*)g;
  char* lb = (char*)lds;
  #pragma unroll
  for (int j = 0; j < 8; j++) {
    int off = j * 4096 + wave * 1024;               // wave-uniform LDS base
    int r = (off >> 8) + (lane >> 4);
    int c = lane & 15;
    const char* gs = gb + (size_t)r * (rstride * 2) + ((c ^ (r & 7)) << 4);
    async_copy16(gs, lb + off);
  }
}

__device__ __forceinline__ bf16x8 lds_frag(const __bf16* base, int row, int chunk) {
  return *reinterpret_cast<const bf16x8*>(
      reinterpret_cast<const char*>(base) + row * 256 + ((chunk ^ (row & 7)) << 4));
}

__global__ __launch_bounds__(256, 1) void attn_fwd(
    const __bf16* __restrict__ Qb, const __bf16* __restrict__ Kb,
    const __bf16* __restrict__ Vtb, __bf16* __restrict__ att_out) {
  __shared__ __bf16 Qs[128 * 128];
  __shared__ __bf16 Ks[128 * 128];
  __shared__ __bf16 Vts[128 * 128];
  __shared__ __bf16 Ps[4 * 32 * 128];   // per-wave P tile [32 q][128 s]
  const int tid = threadIdx.x, lane = tid & 63, wave = tid >> 6;
  const int hi = lane >> 4, lo = lane & 15;
  const int bh = blockIdx.y, b = bh >> 4, h = bh & 15;
  const __bf16* Qg = Qb + (size_t)bh * T_SEQ * DH;
  const __bf16* Kg = Kb + (size_t)bh * T_SEQ * DH;
  const __bf16* Vg = Vtb + (size_t)bh * DH * T_SEQ;
  const float scale = 0.08838834764831845f;   // 1/sqrt(128)
  const float L2E = 1.4426950408889634f;

  for (int pass = 0; pass < 2; ++pass) {
    int qi = pass ? (15 - blockIdx.x) : blockIdx.x;
    int q0 = qi * 128;
    __syncthreads();                           // all waves done with prev pass LDS
    stage_swz(Qg + (size_t)q0 * DH, DH, Qs, tid);
    f32x4 oacc[8][2] = {};
    float m0 = -3e38f, m1 = -3e38f, l0 = 0.f, l1 = 0.f;
    const int qgl0 = q0 + wave * 32 + lo;
    const int qgl1 = qgl0 + 16;

    for (int kt = 0; kt <= qi; ++kt) {
      __syncthreads();                         // prev tile reads done
      stage_swz(Kg + (size_t)kt * 128 * DH, DH, Ks, tid);
      stage_swz(Vg + (size_t)kt * 128, T_SEQ, Vts, tid);
      __syncthreads();                         // drains vmcnt(0): K/V (and Q) ready

      // S^T = K · Q^T : A = K[s][d], B = Q^T[d][q]; C: row=s (hi*4+r), col=q (lo)
      f32x4 sacc[8][2] = {};
      #pragma unroll
      for (int ks = 0; ks < 4; ++ks) {
        bf16x8 bq0 = lds_frag(Qs, wave * 32 + lo, ks * 4 + hi);
        bf16x8 bq1 = lds_frag(Qs, wave * 32 + 16 + lo, ks * 4 + hi);
        #pragma unroll
        for (int sf = 0; sf < 8; ++sf) {
          bf16x8 ak = lds_frag(Ks, sf * 16 + lo, ks * 4 + hi);
          sacc[sf][0] = MFMA16(ak, bq0, sacc[sf][0], 0, 0, 0);
          sacc[sf][1] = MFMA16(ak, bq1, sacc[sf][1], 0, 0, 0);
        }
      }
      const bool diag = (kt == qi);
      #pragma unroll
      for (int qf = 0; qf < 2; ++qf) {
        const int qgl = qf ? qgl1 : qgl0;
        float mold = qf ? m1 : m0;
        float mx = -3e38f;
        #pragma unroll
        for (int sf = 0; sf < 8; ++sf)
          #pragma unroll
          for (int r = 0; r < 4; ++r) {
            float v = sacc[sf][qf][r] * scale;
            if (diag && (kt * 128 + sf * 16 + hi * 4 + r) > qgl) v = -3e38f;
            sacc[sf][qf][r] = v;
            mx = fmaxf(mx, v);
          }
        mx = fmaxf(mx, __shfl_xor(mx, 16, 64));
        mx = fmaxf(mx, __shfl_xor(mx, 32, 64));
        float mnew = fmaxf(mold, mx);
        float alpha = __builtin_exp2f((mold - mnew) * L2E);
        if (qf) m1 = mnew; else m0 = mnew;
        float rs = 0.f;
        #pragma unroll
        for (int sf = 0; sf < 8; ++sf)
          #pragma unroll
          for (int r = 0; r < 4; ++r) {
            float p = __builtin_exp2f((sacc[sf][qf][r] - mnew) * L2E);
            sacc[sf][qf][r] = p;
            rs += p;
          }
        rs += __shfl_xor(rs, 16, 64);
        rs += __shfl_xor(rs, 32, 64);
        if (qf) l1 = l1 * alpha + rs; else l0 = l0 * alpha + rs;
        #pragma unroll
        for (int df = 0; df < 8; ++df) {
          oacc[df][qf][0] *= alpha; oacc[df][qf][1] *= alpha;
          oacc[df][qf][2] *= alpha; oacc[df][qf][3] *= alpha;
        }
        // write P tile: lane's 4 vals are contiguous s at row q_loc -> one b64
        const int q_loc = qf * 16 + lo;
        #pragma unroll
        for (int sf = 0; sf < 8; ++sf) {
          bf16x4 pk;
          pk[0] = (__bf16)sacc[sf][qf][0]; pk[1] = (__bf16)sacc[sf][qf][1];
          pk[2] = (__bf16)sacc[sf][qf][2]; pk[3] = (__bf16)sacc[sf][qf][3];
          int cb = sf * 32 + hi * 8;
          int chunk = cb >> 4, rem = cb & 15;
          char* p = (char*)Ps + wave * 8192 + q_loc * 256 +
                    (((chunk ^ (q_loc & 7)) << 4) | rem);
          *reinterpret_cast<bf16x4*>(p) = pk;
        }
      }
      // PV: O^T += V^T · P^T : A = V^T[d][s] (Vts rows), B = P[q][s] rows
      const __bf16* Pw = Ps + wave * 4096;
      #pragma unroll
      for (int ks = 0; ks < 4; ++ks) {
        bf16x8 bp0 = lds_frag(Pw, lo, ks * 4 + hi);
        bf16x8 bp1 = lds_frag(Pw, 16 + lo, ks * 4 + hi);
        #pragma unroll
        for (int df = 0; df < 8; ++df) {
          bf16x8 av = lds_frag(Vts, df * 16 + lo, ks * 4 + hi);
          oacc[df][0] = MFMA16(av, bp0, oacc[df][0], 0, 0, 0);
          oacc[df][1] = MFMA16(av, bp1, oacc[df][1], 0, 0, 0);
        }
      }
    } // kt

    // epilogue: O^T lane holds d = df*16 + hi*4 + r, q = qf*16 + lo
    #pragma unroll
    for (int qf = 0; qf < 2; ++qf) {
      float inv = 1.0f / (qf ? l1 : l0);
      int qrow = b * T_SEQ + q0 + wave * 32 + qf * 16 + lo;
      #pragma unroll
      for (int df = 0; df < 8; ++df) {
        bf16x4 pk;
        pk[0] = (__bf16)(oacc[df][qf][0] * inv);
        pk[1] = (__bf16)(oacc[df][qf][1] * inv);
        pk[2] = (__bf16)(oacc[df][qf][2] * inv);
        pk[3] = (__bf16)(oacc[df][qf][3] * inv);
        int d = df * 16 + hi * 4;
        *reinterpret_cast<bf16x4*>(att_out + (size_t)qrow * DM + h * DH + d) = pk;
      }
    }
  } // pass
}

// ---------------- launch ----------------

extern "C" void kernel_launch(void* const* d_in, const int* in_sizes, int n_in,
                              void* d_out, int out_size, void* d_ws, size_t ws_size,
                              hipStream_t stream) {
  const float* x     = (const float*)d_in[0];
  // d_in[1] = causal mask: ignored (mask applied analytically)
  const float* fcos  = (const float*)d_in[2];
  const float* fsin  = (const float*)d_in[3];
  const float* Wqkv  = (const float*)d_in[4];
  const float* bqkv  = (const float*)d_in[5];
  const float* Wproj = (const float*)d_in[6];
  const float* bproj = (const float*)d_in[7];
  float* out  = (float*)d_out;
  float* kout = out + (size_t)8388608;
  float* vout = out + (size_t)16777216;

  char* ws = (char*)d_ws;
  __bf16* xb     = (__bf16*)(ws);                 // 16 MiB; reused as att_out later
  __bf16* WqkvT  = (__bf16*)(ws + 16777216);      // 24 MiB
  __bf16* WprojT = (__bf16*)(ws + 41943040);      // 8 MiB
  __bf16* Qb     = (__bf16*)(ws + 50331648);      // 16 MiB
  __bf16* Kb     = (__bf16*)(ws + 67108864);      // 16 MiB
  __bf16* Vb     = (__bf16*)(ws + 83886080);      // 16 MiB
  __bf16* Vtb    = (__bf16*)(ws + 100663296);     // 16 MiB  (total 112 MiB)
  __bf16* att    = xb;                            // alias: xb dead after gemm1

  cast_bf16_k<<<8192, 256, 0, stream>>>(x, xb);
  transpose_cast_w<<<dim3(192, 64), dim3(32, 8), 0, stream>>>(Wqkv, WqkvT, DM, 3 * DM);
  transpose_cast_w<<<dim3(64, 64), dim3(32, 8), 0, stream>>>(Wproj, WprojT, DM, DM);
  // QKV: M=4096 (by 0..15), N=6144 (bx 0..23) -> 384 blocks
  gemm8p<1><<<384, 512, 0, stream>>>(xb, WqkvT, DM, 24, bqkv, fcos, fsin,
                                     Qb, Kb, Vb, kout, vout, nullptr);
  transpose_v<<<dim3(64, 4, NBH), dim3(32, 8), 0, stream>>>(Vb, Vtb);
  attn_fwd<<<dim3(8, NBH), 256, 0, stream>>>(Qb, Kb, Vtb, att);
  // proj: M=4096, N=2048 (bx 0..7) -> 128 blocks
  gemm8p<0><<<128, 512, 0, stream>>>(att, WprojT, DM, 8, bproj, nullptr, nullptr,
                                     nullptr, nullptr, nullptr, nullptr, nullptr, out);
}

// Round 4
// 356.540 us; speedup vs baseline: 1.1554x; 1.1406x over previous
//
#include <hip/hip_runtime.h>
#include <hip/hip_bf16.h>

#define T_SEQ 2048
#define DM    2048
#define NH    16
#define DH    128
#define NBH   32          // B * NH
#define MROWS 4096        // B * T

typedef __bf16 bf16x8 __attribute__((ext_vector_type(8)));
typedef __bf16 bf16x4 __attribute__((ext_vector_type(4)));
typedef float  f32x4  __attribute__((ext_vector_type(4)));

#define MFMA16 __builtin_amdgcn_mfma_f32_16x16x32_bf16

__device__ __forceinline__ void async_copy16(const void* g, void* l) {
  __builtin_amdgcn_global_load_lds((const __attribute__((address_space(1))) void*)g,
                                   (__attribute__((address_space(3))) void*)l, 16, 0, 0);
}

// ---------------- prep kernels ----------------

__global__ void cast_bf16_k(const float* __restrict__ x, __bf16* __restrict__ xb) {
  int i = (blockIdx.x * 256 + threadIdx.x) * 4;
  float4 v = *reinterpret_cast<const float4*>(x + i);
  bf16x4 o;
  o[0] = (__bf16)v.x; o[1] = (__bf16)v.y; o[2] = (__bf16)v.z; o[3] = (__bf16)v.w;
  *reinterpret_cast<bf16x4*>(xb + i) = o;
}

// W [K][N] f32 -> WT [N][K] bf16
__global__ void transpose_cast_w(const float* __restrict__ W, __bf16* __restrict__ WT,
                                 int K, int N) {
  __shared__ float tile[32][33];
  int n0 = blockIdx.x * 32, k0 = blockIdx.y * 32;
  int tx = threadIdx.x, ty = threadIdx.y;
  #pragma unroll
  for (int i = 0; i < 4; i++)
    tile[ty + i * 8][tx] = W[(size_t)(k0 + ty + i * 8) * N + n0 + tx];
  __syncthreads();
  #pragma unroll
  for (int i = 0; i < 4; i++)
    WT[(size_t)(n0 + ty + i * 8) * K + k0 + tx] = (__bf16)tile[tx][ty + i * 8];
}

// Vb [BH][T][D] bf16 -> Vtb [BH][D][T] bf16
__global__ void transpose_v(const __bf16* __restrict__ Vb, __bf16* __restrict__ Vtb) {
  __shared__ __bf16 tile[32][34];
  int t0 = blockIdx.x * 32, d0 = blockIdx.y * 32, bh = blockIdx.z;
  const __bf16* src = Vb + (size_t)bh * T_SEQ * DH;
  __bf16* dst = Vtb + (size_t)bh * DH * T_SEQ;
  int tx = threadIdx.x, ty = threadIdx.y;
  #pragma unroll
  for (int i = 0; i < 4; i++)
    tile[ty + i * 8][tx] = src[(size_t)(t0 + ty + i * 8) * DH + d0 + tx];
  __syncthreads();
  #pragma unroll
  for (int i = 0; i < 4; i++)
    dst[(size_t)(d0 + ty + i * 8) * T_SEQ + t0 + tx] = tile[tx][ty + i * 8];
}

// ------- GEMM (C = A * Bt^T), BM=BN=128, BK=64, 4 waves, 1 barrier/K-tile -------
// LDS tile [128 rows][64 bf16] = 128-B rows, chunk-XOR swizzled: LDS slot s of
// row r holds global chunk s ^ (r&7). Staged via global_load_lds (linear dest,
// inverse-swizzled global source); reads apply the same XOR. A b128 fragment
// read (16 rows x 1 chunk-id) touches all 32 banks evenly (2 lanes/bank = free).

__device__ __forceinline__ bf16x8 rds(const __bf16* base, int row, int chunk) {
  return *reinterpret_cast<const bf16x8*>(
      reinterpret_cast<const char*>(base) + row * 128 + ((chunk ^ (row & 7)) << 4));
}

// stage one 128x64 tile (16 KB): 4 global_load_lds per wave
__device__ __forceinline__ void stage64(const __bf16* g, int K, int kt, char* lds,
                                        int wave, int lane) {
  #pragma unroll
  for (int j = 0; j < 4; j++) {
    int r = wave * 32 + j * 8 + (lane >> 3);
    int c = lane & 7;
    const char* src = (const char*)g + (size_t)r * (K * 2) + kt * 128 + ((c ^ (r & 7)) << 4);
    async_copy16(src, lds + wave * 4096 + j * 1024);
  }
}

template <int EPI>
__global__ __launch_bounds__(256, 2) void gemm_bt(
    const __bf16* __restrict__ A, const __bf16* __restrict__ Bt, int K,
    const float* __restrict__ bias,
    const float* __restrict__ fcos, const float* __restrict__ fsin,
    __bf16* __restrict__ Qb, __bf16* __restrict__ Kb, __bf16* __restrict__ Vb,
    float* __restrict__ kout, float* __restrict__ vout,
    float* __restrict__ outp) {
  __shared__ __bf16 As[2][128 * 64];   // 2 x 16 KB
  __shared__ __bf16 Bs[2][128 * 64];   // 2 x 16 KB  (64 KB total -> 2 blocks/CU)
  const int tid = threadIdx.x, lane = tid & 63, wave = tid >> 6;
  const int hi = lane >> 4, lo = lane & 15;
  const int wm = (wave >> 1) * 64, wn = (wave & 1) * 64;
  const __bf16* Ab = A + (size_t)blockIdx.y * 128 * K;
  const __bf16* Bb = Bt + (size_t)blockIdx.x * 128 * K;
  f32x4 acc[4][4] = {};
  const int NK = K >> 6;

  stage64(Ab, K, 0, (char*)As[0], wave, lane);
  stage64(Bb, K, 0, (char*)Bs[0], wave, lane);
  __syncthreads();   // drains vmcnt: tile 0 ready

  for (int t = 0; t < NK; ++t) {
    const int cur = t & 1;
    if (t + 1 < NK) {
      stage64(Ab, K, t + 1, (char*)As[cur ^ 1], wave, lane);
      stage64(Bb, K, t + 1, (char*)Bs[cur ^ 1], wave, lane);
    }
    // k-chunk 0 (cols 0..31): chunk ids 0..3
    bf16x8 a0[4], b0[4], a1[4], b1[4];
    #pragma unroll
    for (int m = 0; m < 4; ++m) a0[m] = rds(As[cur], wm + m * 16 + lo, hi);
    #pragma unroll
    for (int n = 0; n < 4; ++n) b0[n] = rds(Bs[cur], wn + n * 16 + lo, hi);
    __builtin_amdgcn_s_setprio(1);
    #pragma unroll
    for (int m = 0; m < 4; ++m)
      #pragma unroll
      for (int n = 0; n < 4; ++n)
        acc[m][n] = MFMA16(a0[m], b0[n], acc[m][n], 0, 0, 0);
    __builtin_amdgcn_s_setprio(0);
    // k-chunk 1 (cols 32..63): chunk ids 4..7
    #pragma unroll
    for (int m = 0; m < 4; ++m) a1[m] = rds(As[cur], wm + m * 16 + lo, 4 + hi);
    #pragma unroll
    for (int n = 0; n < 4; ++n) b1[n] = rds(Bs[cur], wn + n * 16 + lo, 4 + hi);
    __builtin_amdgcn_s_setprio(1);
    #pragma unroll
    for (int m = 0; m < 4; ++m)
      #pragma unroll
      for (int n = 0; n < 4; ++n)
        acc[m][n] = MFMA16(a1[m], b1[n], acc[m][n], 0, 0, 0);
    __builtin_amdgcn_s_setprio(0);
    // single barrier per K-tile: all reads of cur done; next-tile staging
    // (issued at top) drains via the implicit vmcnt(0) here.
    __syncthreads();
  }

  // epilogue. C frag layout: row = hi*4 + r, col = lo (verified m89/m91)
  #pragma unroll
  for (int j = 0; j < 4; j++) {
    int n = blockIdx.x * 128 + wn + j * 16 + lo;
    float bv = bias[n];
    if (EPI == 1) {
      int which = n >> 11, wn2 = n & 2047, h = wn2 >> 7, d = wn2 & 127, jj = d >> 1;
      #pragma unroll
      for (int i = 0; i < 4; i++) {
        #pragma unroll
        for (int r = 0; r < 4; r++) {
          int row = blockIdx.y * 128 + wm + i * 16 + hi * 4 + r;
          int b = row >> 11, tt = row & 2047;
          float v = acc[i][j][r] + bv;
          float other = __shfl_xor(v, 1, 64);   // rope pair partner (cols n, n^1)
          float res = v;
          if (which < 2) {
            float c = fcos[tt * 64 + jj], s = fsin[tt * 64 + jj];
            res = (d & 1) ? (other * s + v * c) : (v * c - other * s);
          }
          size_t idx = (((size_t)(b * NH + h)) * T_SEQ + tt) * DH + d;
          if (which == 0) {
            Qb[idx] = (__bf16)res;
          } else if (which == 1) {
            Kb[idx] = (__bf16)res; kout[idx] = res;
          } else {
            Vb[idx] = (__bf16)res; vout[idx] = res;
          }
        }
      }
    } else {
      #pragma unroll
      for (int i = 0; i < 4; i++) {
        #pragma unroll
        for (int r = 0; r < 4; r++) {
          int row = blockIdx.y * 128 + wm + i * 16 + hi * 4 + r;
          outp[(size_t)row * DM + n] = acc[i][j][r] + bv;
        }
      }
    }
  }
}

// ---------------- flash attention ----------------
// LDS tiles are [128 rows][256B rows], chunk-swizzled: chunk' = chunk ^ (row&7).
// Staged via global_load_lds (linear dest) with inverse-swizzled global source.

__device__ __forceinline__ void stage_swz(const __bf16* g, int rstride,
                                          __bf16* lds, int tid) {
  const int wave = tid >> 6, lane = tid & 63;
  const char* gb = (const char*)g;
  char* lb = (char*)lds;
  #pragma unroll
  for (int j = 0; j < 8; j++) {
    int off = j * 4096 + wave * 1024;               // wave-uniform LDS base
    int r = (off >> 8) + (lane >> 4);
    int c = lane & 15;
    const char* gs = gb + (size_t)r * (rstride * 2) + ((c ^ (r & 7)) << 4);
    async_copy16(gs, lb + off);
  }
}

__device__ __forceinline__ bf16x8 lds_frag(const __bf16* base, int row, int chunk) {
  return *reinterpret_cast<const bf16x8*>(
      reinterpret_cast<const char*>(base) + row * 256 + ((chunk ^ (row & 7)) << 4));
}

__global__ __launch_bounds__(256, 1) void attn_fwd(
    const __bf16* __restrict__ Qb, const __bf16* __restrict__ Kb,
    const __bf16* __restrict__ Vtb, __bf16* __restrict__ att_out) {
  __shared__ __bf16 Qs[128 * 128];
  __shared__ __bf16 Ks[128 * 128];
  __shared__ __bf16 Vts[128 * 128];
  __shared__ __bf16 Ps[4 * 32 * 128];   // per-wave P tile [32 q][128 s]
  const int tid = threadIdx.x, lane = tid & 63, wave = tid >> 6;
  const int hi = lane >> 4, lo = lane & 15;
  const int bh = blockIdx.y, b = bh >> 4, h = bh & 15;
  const __bf16* Qg = Qb + (size_t)bh * T_SEQ * DH;
  const __bf16* Kg = Kb + (size_t)bh * T_SEQ * DH;
  const __bf16* Vg = Vtb + (size_t)bh * DH * T_SEQ;
  const float scale = 0.08838834764831845f;   // 1/sqrt(128)
  const float L2E = 1.4426950408889634f;

  for (int pass = 0; pass < 2; ++pass) {
    int qi = pass ? (15 - blockIdx.x) : blockIdx.x;
    int q0 = qi * 128;
    __syncthreads();                           // all waves done with prev pass LDS
    stage_swz(Qg + (size_t)q0 * DH, DH, Qs, tid);
    f32x4 oacc[8][2] = {};
    float m0 = -3e38f, m1 = -3e38f, l0 = 0.f, l1 = 0.f;
    const int qgl0 = q0 + wave * 32 + lo;
    const int qgl1 = qgl0 + 16;

    for (int kt = 0; kt <= qi; ++kt) {
      __syncthreads();                         // prev tile reads done
      stage_swz(Kg + (size_t)kt * 128 * DH, DH, Ks, tid);
      stage_swz(Vg + (size_t)kt * 128, T_SEQ, Vts, tid);
      __syncthreads();                         // drains vmcnt(0): K/V (and Q) ready

      // S^T = K · Q^T : A = K[s][d], B = Q^T[d][q]; C: row=s (hi*4+r), col=q (lo)
      f32x4 sacc[8][2] = {};
      #pragma unroll
      for (int ks = 0; ks < 4; ++ks) {
        bf16x8 bq0 = lds_frag(Qs, wave * 32 + lo, ks * 4 + hi);
        bf16x8 bq1 = lds_frag(Qs, wave * 32 + 16 + lo, ks * 4 + hi);
        #pragma unroll
        for (int sf = 0; sf < 8; ++sf) {
          bf16x8 ak = lds_frag(Ks, sf * 16 + lo, ks * 4 + hi);
          sacc[sf][0] = MFMA16(ak, bq0, sacc[sf][0], 0, 0, 0);
          sacc[sf][1] = MFMA16(ak, bq1, sacc[sf][1], 0, 0, 0);
        }
      }
      const bool diag = (kt == qi);
      #pragma unroll
      for (int qf = 0; qf < 2; ++qf) {
        const int qgl = qf ? qgl1 : qgl0;
        float mold = qf ? m1 : m0;
        float mx = -3e38f;
        #pragma unroll
        for (int sf = 0; sf < 8; ++sf)
          #pragma unroll
          for (int r = 0; r < 4; ++r) {
            float v = sacc[sf][qf][r] * scale;
            if (diag && (kt * 128 + sf * 16 + hi * 4 + r) > qgl) v = -3e38f;
            sacc[sf][qf][r] = v;
            mx = fmaxf(mx, v);
          }
        mx = fmaxf(mx, __shfl_xor(mx, 16, 64));
        mx = fmaxf(mx, __shfl_xor(mx, 32, 64));
        float mnew = fmaxf(mold, mx);
        float alpha = __builtin_exp2f((mold - mnew) * L2E);
        if (qf) m1 = mnew; else m0 = mnew;
        float rs = 0.f;
        #pragma unroll
        for (int sf = 0; sf < 8; ++sf)
          #pragma unroll
          for (int r = 0; r < 4; ++r) {
            float p = __builtin_exp2f((sacc[sf][qf][r] - mnew) * L2E);
            sacc[sf][qf][r] = p;
            rs += p;
          }
        rs += __shfl_xor(rs, 16, 64);
        rs += __shfl_xor(rs, 32, 64);
        if (qf) l1 = l1 * alpha + rs; else l0 = l0 * alpha + rs;
        #pragma unroll
        for (int df = 0; df < 8; ++df) {
          oacc[df][qf][0] *= alpha; oacc[df][qf][1] *= alpha;
          oacc[df][qf][2] *= alpha; oacc[df][qf][3] *= alpha;
        }
        // write P tile: lane's 4 vals are contiguous s at row q_loc -> one b64
        const int q_loc = qf * 16 + lo;
        #pragma unroll
        for (int sf = 0; sf < 8; ++sf) {
          bf16x4 pk;
          pk[0] = (__bf16)sacc[sf][qf][0]; pk[1] = (__bf16)sacc[sf][qf][1];
          pk[2] = (__bf16)sacc[sf][qf][2]; pk[3] = (__bf16)sacc[sf][qf][3];
          int cb = sf * 32 + hi * 8;
          int chunk = cb >> 4, rem = cb & 15;
          char* p = (char*)Ps + wave * 8192 + q_loc * 256 +
                    (((chunk ^ (q_loc & 7)) << 4) | rem);
          *reinterpret_cast<bf16x4*>(p) = pk;
        }
      }
      // PV: O^T += V^T · P^T : A = V^T[d][s] (Vts rows), B = P[q][s] rows
      const __bf16* Pw = Ps + wave * 4096;
      #pragma unroll
      for (int ks = 0; ks < 4; ++ks) {
        bf16x8 bp0 = lds_frag(Pw, lo, ks * 4 + hi);
        bf16x8 bp1 = lds_frag(Pw, 16 + lo, ks * 4 + hi);
        #pragma unroll
        for (int df = 0; df < 8; ++df) {
          bf16x8 av = lds_frag(Vts, df * 16 + lo, ks * 4 + hi);
          oacc[df][0] = MFMA16(av, bp0, oacc[df][0], 0, 0, 0);
          oacc[df][1] = MFMA16(av, bp1, oacc[df][1], 0, 0, 0);
        }
      }
    } // kt

    // epilogue: O^T lane holds d = df*16 + hi*4 + r, q = qf*16 + lo
    #pragma unroll
    for (int qf = 0; qf < 2; ++qf) {
      float inv = 1.0f / (qf ? l1 : l0);
      int qrow = b * T_SEQ + q0 + wave * 32 + qf * 16 + lo;
      #pragma unroll
      for (int df = 0; df < 8; ++df) {
        bf16x4 pk;
        pk[0] = (__bf16)(oacc[df][qf][0] * inv);
        pk[1] = (__bf16)(oacc[df][qf][1] * inv);
        pk[2] = (__bf16)(oacc[df][qf][2] * inv);
        pk[3] = (__bf16)(oacc[df][qf][3] * inv);
        int d = df * 16 + hi * 4;
        *reinterpret_cast<bf16x4*>(att_out + (size_t)qrow * DM + h * DH + d) = pk;
      }
    }
  } // pass
}

// ---------------- launch ----------------

extern "C" void kernel_launch(void* const* d_in, const int* in_sizes, int n_in,
                              void* d_out, int out_size, void* d_ws, size_t ws_size,
                              hipStream_t stream) {
  const float* x     = (const float*)d_in[0];
  // d_in[1] = causal mask: ignored (mask applied analytically)
  const float* fcos  = (const float*)d_in[2];
  const float* fsin  = (const float*)d_in[3];
  const float* Wqkv  = (const float*)d_in[4];
  const float* bqkv  = (const float*)d_in[5];
  const float* Wproj = (const float*)d_in[6];
  const float* bproj = (const float*)d_in[7];
  float* out  = (float*)d_out;
  float* kout = out + (size_t)8388608;
  float* vout = out + (size_t)16777216;

  char* ws = (char*)d_ws;
  __bf16* xb     = (__bf16*)(ws);                 // 16 MiB; reused as att_out later
  __bf16* WqkvT  = (__bf16*)(ws + 16777216);      // 24 MiB
  __bf16* WprojT = (__bf16*)(ws + 41943040);      // 8 MiB
  __bf16* Qb     = (__bf16*)(ws + 50331648);      // 16 MiB
  __bf16* Kb     = (__bf16*)(ws + 67108864);      // 16 MiB
  __bf16* Vb     = (__bf16*)(ws + 83886080);      // 16 MiB
  __bf16* Vtb    = (__bf16*)(ws + 100663296);     // 16 MiB  (total 112 MiB)
  __bf16* att    = xb;                            // alias: xb dead after gemm1

  cast_bf16_k<<<8192, 256, 0, stream>>>(x, xb);
  transpose_cast_w<<<dim3(192, 64), dim3(32, 8), 0, stream>>>(Wqkv, WqkvT, DM, 3 * DM);
  transpose_cast_w<<<dim3(64, 64), dim3(32, 8), 0, stream>>>(Wproj, WprojT, DM, DM);
  // QKV: M=4096 (by 0..31), N=6144 (bx 0..47) -> 1536 blocks, ~3 rounds of 2/CU
  gemm_bt<1><<<dim3(48, 32), 256, 0, stream>>>(xb, WqkvT, DM, bqkv, fcos, fsin,
                                               Qb, Kb, Vb, kout, vout, nullptr);
  transpose_v<<<dim3(64, 4, NBH), dim3(32, 8), 0, stream>>>(Vb, Vtb);
  attn_fwd<<<dim3(8, NBH), 256, 0, stream>>>(Qb, Kb, Vtb, att);
  // proj: M=4096, N=2048 -> 16x32 = 512 blocks
  gemm_bt<0><<<dim3(16, 32), 256, 0, stream>>>(att, WprojT, DM, bproj, nullptr, nullptr,
                                               nullptr, nullptr, nullptr, nullptr, nullptr, out);
}